// Round 13
// baseline (202.396 us; speedup 1.0000x reference)
//
#include <hip/hip_runtime.h>
#include <hip/hip_bf16.h>
#include <stdint.h>

#define S_DIM 2048
#define E_DIM 2048
#define H_NUM 16
#define D_HEAD 128
#define N3E 6144

typedef __attribute__((ext_vector_type(8))) short short8;
typedef __attribute__((ext_vector_type(4))) float f32x4;
typedef __attribute__((ext_vector_type(8))) unsigned short ushort8;

#define GLD16(src, dst)                                                          \
    __builtin_amdgcn_global_load_lds((const __attribute__((address_space(1))) void*)(src), \
                                     (__attribute__((address_space(3))) void*)(dst), 16, 0, 0)

__device__ __forceinline__ unsigned short f32_to_bf16_bits(float f) {
    __hip_bfloat16 b = __float2bfloat16(f);
    unsigned short u;
    __builtin_memcpy(&u, &b, 2);
    return u;
}
__device__ __forceinline__ float bf16_bits_to_f32(unsigned short u) {
    unsigned int v = ((unsigned int)u) << 16;
    float f;
    __builtin_memcpy(&f, &v, 4);
    return f;
}

// ---------------- convert f32 -> bf16 (vectorized, 8 elems/thread) ----------
__global__ void k_convert(const float* __restrict__ in, __hip_bfloat16* __restrict__ out, int n) {
    int i = (blockIdx.x * 256 + threadIdx.x) * 8;
    if (i >= n) return;
    float4 a = *(const float4*)(in + i);
    float4 b = *(const float4*)(in + i + 4);
    ushort8 o;
    o[0] = f32_to_bf16_bits(a.x);
    o[1] = f32_to_bf16_bits(a.y);
    o[2] = f32_to_bf16_bits(a.z);
    o[3] = f32_to_bf16_bits(a.w);
    o[4] = f32_to_bf16_bits(b.x);
    o[5] = f32_to_bf16_bits(b.y);
    o[6] = f32_to_bf16_bits(b.z);
    o[7] = f32_to_bf16_bits(b.w);
    *(ushort8*)(out + i) = o;
}

// ------------- transpose + convert: in [R][C] f32 -> out [C][R] bf16 --------
__global__ void k_transpose_convert(const float* __restrict__ in, __hip_bfloat16* __restrict__ out,
                                    int R, int C) {
    __shared__ float tile[32][33];
    int c0 = blockIdx.x * 32, r0 = blockIdx.y * 32;
    int tx = threadIdx.x, ty = threadIdx.y;  // block (32,8)
#pragma unroll
    for (int i = 0; i < 4; ++i) {
        int r = r0 + ty + i * 8;
        tile[ty + i * 8][tx] = in[(size_t)r * C + c0 + tx];
    }
    __syncthreads();
#pragma unroll
    for (int i = 0; i < 4; ++i) {
        int c = c0 + ty + i * 8;
        out[(size_t)c * R + r0 + tx] = __float2bfloat16(tile[tx][ty + i * 8]);
    }
}

// ------------- transpose v slice of qkv (bf16): vT[hd][t] = qkv[t][4096+hd] --
__global__ void k_transpose_v(const __hip_bfloat16* __restrict__ qkv, __hip_bfloat16* __restrict__ vT) {
    __shared__ __hip_bfloat16 tile[32][33];
    int c0 = blockIdx.x * 32, t0 = blockIdx.y * 32;
    int tx = threadIdx.x, ty = threadIdx.y;  // block (32,8)
#pragma unroll
    for (int i = 0; i < 4; ++i) {
        int t = t0 + ty + i * 8;
        tile[ty + i * 8][tx] = qkv[(size_t)t * N3E + 2 * E_DIM + c0 + tx];
    }
    __syncthreads();
#pragma unroll
    for (int i = 0; i < 4; ++i) {
        int c = c0 + ty + i * 8;
        vT[(size_t)c * S_DIM + t0 + tx] = tile[tx][ty + i * 8];
    }
}

// ======================= 128x128 pipelined GEMM (both GEMMs) =================
// 4-buf BK=32 ring, counted vmcnt(8), 1 barrier/K-tile, XCD-swizzled 1-D grid
// (requires grid%8==0). 64KB LDS -> 2 blocks/CU; at grid > 256 two resident
// blocks per CU interleave phases freely (inter-block overlap).
template <int EPI>
__global__ __launch_bounds__(256, 2) void k_gemm128(const __hip_bfloat16* __restrict__ A,
                                                    const __hip_bfloat16* __restrict__ Bt,
                                                    const float* __restrict__ bias,
                                                    float* __restrict__ outF,
                                                    __hip_bfloat16* __restrict__ outB,
                                                    int M, int N, int K) {
    __shared__ __hip_bfloat16 As[4][128 * 32];
    __shared__ __hip_bfloat16 Bs[4][128 * 32];

    const int tid = threadIdx.x;
    const int w = tid >> 6, lane = tid & 63;
    const int lg = lane >> 4, l16 = lane & 15;
    const int wr = w >> 1, wc = w & 1;  // wave grid 2 (M) x 2 (N)
    const int ntx = N >> 7;
    const int chunk = ((M >> 7) * ntx) >> 3;
    const int lin = blockIdx.x;
    const int swz = (lin & 7) * chunk + (lin >> 3);
    const int m0 = (swz / ntx) << 7, n0 = (swz % ntx) << 7;
    const int NT = K >> 5;

    const int srow = tid >> 2;
    const int scol = ((tid & 3) ^ ((tid >> 3) & 3)) * 8;
    const __hip_bfloat16* aB = A + (size_t)(m0 + srow) * K + scol;
    const __hip_bfloat16* bB = Bt + (size_t)(n0 + srow) * K + scol;
    const size_t rstep = (size_t)64 * K;

#define STG(u, p)                                                                                     \
    do {                                                                                              \
        GLD16(aB + (p) * rstep + (u) * 32, &As[(u) & 3][(p) * 2048 + tid * 8]);                       \
        GLD16(bB + (p) * rstep + (u) * 32, &Bs[(u) & 3][(p) * 2048 + tid * 8]);                       \
    } while (0)

    f32x4 acc[4][4];
#pragma unroll
    for (int i = 0; i < 4; ++i)
#pragma unroll
        for (int j = 0; j < 4; ++j) acc[i][j] = {0.f, 0.f, 0.f, 0.f};

    STG(0, 0); STG(0, 1);
    STG(1, 0); STG(1, 1);
    STG(2, 0); STG(2, 1);
    asm volatile("s_waitcnt vmcnt(8)" ::: "memory");
    __builtin_amdgcn_s_barrier();

    short8 af[4], bfr[4];
    for (int t = 0; t < NT; ++t) {
        const int cur = t & 3;
        const int u = t + 3;
#pragma unroll
        for (int i = 0; i < 4; ++i) {
            int arow = wr * 64 + i * 16 + l16;
            af[i] = *(const short8*)&As[cur][arow * 32 + ((lg ^ ((arow >> 1) & 3)) * 8)];
            int brow = wc * 64 + i * 16 + l16;
            bfr[i] = *(const short8*)&Bs[cur][brow * 32 + ((lg ^ ((brow >> 1) & 3)) * 8)];
        }
        if (u < NT) { STG(u, 0); STG(u, 1); }
        __builtin_amdgcn_s_setprio(1);
#pragma unroll
        for (int mi = 0; mi < 4; ++mi)
#pragma unroll
            for (int ni = 0; ni < 4; ++ni)
                acc[mi][ni] = __builtin_amdgcn_mfma_f32_16x16x32_bf16(af[mi], bfr[ni], acc[mi][ni], 0, 0, 0);
        __builtin_amdgcn_s_setprio(0);
        __builtin_amdgcn_sched_barrier(0);
        if (t < NT - 3)
            asm volatile("s_waitcnt vmcnt(8)" ::: "memory");
        else if (t == NT - 3)
            asm volatile("s_waitcnt vmcnt(4)" ::: "memory");
        else if (t == NT - 2)
            asm volatile("s_waitcnt vmcnt(0)" ::: "memory");
        __builtin_amdgcn_sched_barrier(0);
        __builtin_amdgcn_s_barrier();
    }
#undef STG

    const size_t OFF_K = (size_t)S_DIM * E_DIM;
    const size_t OFF_V = 2 * (size_t)S_DIM * E_DIM;
#pragma unroll
    for (int ni = 0; ni < 4; ++ni) {
        int jcol = n0 + wc * 64 + ni * 16 + l16;
        float bj = bias[jcol];
#pragma unroll
        for (int mi = 0; mi < 4; ++mi) {
#pragma unroll
            for (int r = 0; r < 4; ++r) {
                int s = m0 + wr * 64 + mi * 16 + lg * 4 + r;
                float v = acc[mi][ni][r] + bj;
                if (EPI == 1) {
                    outB[(size_t)s * N + jcol] = __float2bfloat16(v);
                    if (jcol >= 2 * E_DIM) {
                        outF[OFF_V + (size_t)s * E_DIM + (jcol - 2 * E_DIM)] = v;
                    } else if (jcol >= E_DIM) {
                        outF[OFF_K + (size_t)s * E_DIM + (jcol - E_DIM)] = v;
                    }
                } else {
                    outF[(size_t)s * N + jcol] = v;
                }
            }
        }
    }
}

// ---------------- flash attention (causal), split-KV, fixed-max softmax -----
// R10's proven sync structure, KVBLK=32: LDS 36.5KB -> 4 blocks/CU.
__global__ __launch_bounds__(256) void k_attn(const __hip_bfloat16* __restrict__ qkv,   // [S][6144]
                                              const __hip_bfloat16* __restrict__ vT,    // [2048][2048]
                                              __hip_bfloat16* __restrict__ concat,      // [S][2048]
                                              __hip_bfloat16* __restrict__ Ob,          // [512][64][128]
                                              float* __restrict__ ml) {                 // [512][64][2]
    const int h = blockIdx.y;
    const int xs = 47 - (int)blockIdx.x;  // longest-work-first-ish dispatch
    int x, tstart, tend, chunk = 0;       // tstart/tend in units of 32-kv tiles
    bool split;
    if (xs < 16) {
        x = xs; tstart = 0; tend = 2 * (x + 1); split = false;
    } else {
        int idx = xs - 16;
        x = 16 + (idx >> 1);
        chunk = idx & 1;
        int L = 2 * (x + 1), half = L >> 1;
        tstart = chunk ? half : 0;
        tend = chunk ? L : half;
        split = true;
    }
    const int q0 = x * 64;
    const int tid = threadIdx.x;
    const int w = tid >> 6, lane = tid & 63;
    const int lg = lane >> 4, l16 = lane & 15;
    const int sbase = q0 + w * 16;
    const float scale = 0.08838834764831845f;  // 1/sqrt(128)
    const float FIXM = 8.0f;

    __shared__ __hip_bfloat16 Ks[2][32 * 128];  // [t][d], swizzled (16-slot rows, ^kr&7)
    __shared__ __hip_bfloat16 Vs[2][128 * 32];  // [d][t], swizzled (4-slot rows, ^d&3)
    __shared__ __hip_bfloat16 plds[4][16 * 36];

    short8 qa[4];
#pragma unroll
    for (int kc = 0; kc < 4; ++kc)
        qa[kc] = *(const short8*)&qkv[(size_t)(sbase + l16) * N3E + h * D_HEAD + kc * 32 + lg * 8];

    short8 ones;
#pragma unroll
    for (int j = 0; j < 8; ++j) ones[j] = (short)0x3F80;  // bf16 1.0

    f32x4 O[8];
#pragma unroll
    for (int i = 0; i < 8; ++i) O[i] = {0.f, 0.f, 0.f, 0.f};
    f32x4 accL = {0.f, 0.f, 0.f, 0.f};  // row-sum of P (replicated over lanes)

    auto stage = [&](int buf, int it) {
        const int t0 = it * 32;
#pragma unroll
        for (int j = 0; j < 2; ++j) {
            int kr = j * 16 + w * 4 + (lane >> 4);
            int ks16 = (lane & 15) ^ (kr & 7);
            const __hip_bfloat16* gk = qkv + (size_t)(t0 + kr) * N3E + E_DIM + h * D_HEAD + ks16 * 8;
            GLD16(gk, &Ks[buf][j * 2048 + w * 512]);
            int vd = j * 64 + w * 16 + (lane >> 2);
            int vs4 = (lane & 3) ^ (vd & 3);
            const __hip_bfloat16* gv = vT + (size_t)(h * D_HEAD + vd) * S_DIM + t0 + vs4 * 8;
            GLD16(gv, &Vs[buf][j * 2048 + w * 512]);
        }
    };

    stage(0, tstart);
    int cur = 0;

    for (int it = tstart; it < tend; ++it) {
        const int t0 = it * 32;
        __syncthreads();  // vmcnt drained: buf[cur] ready; all waves done with buf[cur^1]
        if (it + 1 < tend) stage(cur ^ 1, it + 1);
        const bool diag = (t0 >= q0);

        // ---- QK^T from LDS (swizzled reads): 2 col-tiles x 4 kc = 8 MFMA ----
        f32x4 sc[2];
        __builtin_amdgcn_s_setprio(1);
#pragma unroll
        for (int f = 0; f < 2; ++f) {
            sc[f] = {0.f, 0.f, 0.f, 0.f};
            int r = f * 16 + l16;
#pragma unroll
            for (int kc = 0; kc < 4; ++kc) {
                int ce = (kc * 32 + lg * 8) ^ ((r & 7) << 3);
                short8 kb = *(const short8*)&Ks[cur][r * 128 + ce];
                sc[f] = __builtin_amdgcn_mfma_f32_16x16x32_bf16(qa[kc], kb, sc[f], 0, 0, 0);
            }
        }
        __builtin_amdgcn_s_setprio(0);

        // ---- fixed-max softmax: p = exp(s*scale - 8); no reductions ----
#pragma unroll
        for (int f = 0; f < 2; ++f) {
#pragma unroll
            for (int r = 0; r < 4; ++r) {
                float v = sc[f][r] * scale - FIXM;
                if (diag) {
                    int t = t0 + f * 16 + l16;
                    int s = sbase + lg * 4 + r;
                    if (t > s) v = -1e30f;
                }
                sc[f][r] = __expf(v);
            }
        }

        // ---- P (C-layout) -> LDS -> A-layout fragment ----
#pragma unroll
        for (int f = 0; f < 2; ++f)
#pragma unroll
            for (int r = 0; r < 4; ++r)
                plds[w][(lg * 4 + r) * 36 + f * 16 + l16] = __float2bfloat16(sc[f][r]);
        short8 pa = *(const short8*)&plds[w][l16 * 36 + lg * 8];

        // ---- PV (8) + row-sum (1) from LDS (swizzled reads) ----
        __builtin_amdgcn_s_setprio(1);
        accL = __builtin_amdgcn_mfma_f32_16x16x32_bf16(pa, ones, accL, 0, 0, 0);
#pragma unroll
        for (int f2 = 0; f2 < 8; ++f2) {
            int d = f2 * 16 + l16;
            int ce = (lg ^ (d & 3)) * 8;
            short8 vb = *(const short8*)&Vs[cur][d * 32 + ce];
            O[f2] = __builtin_amdgcn_mfma_f32_16x16x32_bf16(pa, vb, O[f2], 0, 0, 0);
        }
        __builtin_amdgcn_s_setprio(0);
        cur ^= 1;
    }

    if (!split) {
#pragma unroll
        for (int f2 = 0; f2 < 8; ++f2) {
#pragma unroll
            for (int r = 0; r < 4; ++r) {
                int s = sbase + lg * 4 + r;
                float v = O[f2][r] / accL[r];
                concat[(size_t)s * E_DIM + h * D_HEAD + f2 * 16 + l16] = __float2bfloat16(v);
            }
        }
    } else {
        const int sub = (h * 16 + (x - 16)) * 2 + chunk;
#pragma unroll
        for (int f2 = 0; f2 < 8; ++f2) {
#pragma unroll
            for (int r = 0; r < 4; ++r) {
                int row = w * 16 + lg * 4 + r;
                Ob[(size_t)sub * 8192 + row * 128 + f2 * 16 + l16] = __float2bfloat16(O[f2][r]);
            }
        }
        if (l16 == 0) {
#pragma unroll
            for (int r = 0; r < 4; ++r) {
                int row = w * 16 + lg * 4 + r;
                ml[((size_t)sub * 64 + row) * 2 + 0] = FIXM;
                ml[((size_t)sub * 64 + row) * 2 + 1] = accL[r];
            }
        }
    }
}

// ---------------- combine two KV-split partials -> concat -------------------
__global__ __launch_bounds__(256) void k_combine(const __hip_bfloat16* __restrict__ Ob,
                                                 const float* __restrict__ ml,
                                                 __hip_bfloat16* __restrict__ concat) {
    const int xx = blockIdx.x;  // 0..15 -> x = xx+16
    const int h = blockIdx.y;
    const int tid = threadIdx.x;
    const int row = tid >> 2;
    const int d0 = (tid & 3) * 32;
    const int sub0 = (h * 16 + xx) * 2, sub1 = sub0 + 1;
    const float m0 = ml[((size_t)sub0 * 64 + row) * 2 + 0];
    const float l0 = ml[((size_t)sub0 * 64 + row) * 2 + 1];
    const float m1 = ml[((size_t)sub1 * 64 + row) * 2 + 0];
    const float l1 = ml[((size_t)sub1 * 64 + row) * 2 + 1];
    const float M = fmaxf(m0, m1);
    const float w0 = __expf(m0 - M), w1 = __expf(m1 - M);
    const float inv = 1.f / (w0 * l0 + w1 * l1);
    const int s = (xx + 16) * 64 + row;
#pragma unroll
    for (int j = 0; j < 32; j += 8) {
        ushort8 a = *(const ushort8*)&Ob[(size_t)sub0 * 8192 + row * 128 + d0 + j];
        ushort8 b = *(const ushort8*)&Ob[(size_t)sub1 * 8192 + row * 128 + d0 + j];
        ushort8 o;
#pragma unroll
        for (int q = 0; q < 8; ++q) {
            float fa = bf16_bits_to_f32(a[q]);
            float fb = bf16_bits_to_f32(b[q]);
            o[q] = f32_to_bf16_bits((w0 * fa + w1 * fb) * inv);
        }
        *(ushort8*)&concat[(size_t)s * E_DIM + h * D_HEAD + d0 + j] = o;
    }
}

extern "C" void kernel_launch(void* const* d_in, const int* in_sizes, int n_in,
                              void* d_out, int out_size, void* d_ws, size_t ws_size,
                              hipStream_t stream) {
    const float* x = (const float*)d_in[0];
    const float* W_attn = (const float*)d_in[1];
    const float* b_attn = (const float*)d_in[2];
    const float* W_proj = (const float*)d_in[3];
    const float* b_proj = (const float*)d_in[4];
    float* out = (float*)d_out;

    __hip_bfloat16* xb = (__hip_bfloat16*)d_ws;                    // 2048x2048
    __hip_bfloat16* WaT = xb + (size_t)S_DIM * E_DIM;              // 6144x2048
    __hip_bfloat16* WpT = WaT + (size_t)N3E * E_DIM;               // 2048x2048
    __hip_bfloat16* qkvb = WpT + (size_t)E_DIM * E_DIM;            // 2048x6144
    __hip_bfloat16* vT = qkvb + (size_t)S_DIM * N3E;               // 2048x2048
    __hip_bfloat16* concat = xb;                                   // alias (xb dead after GEMM1)
    __hip_bfloat16* Ob = WaT;                                      // 512 x 64 x 128 bf16
    float* ml = (float*)(WaT + (size_t)512 * 8192);                // 512 x 64 x 2 f32

    k_convert<<<dim3((S_DIM * E_DIM) / (256 * 8)), dim3(256), 0, stream>>>(x, xb, S_DIM * E_DIM);
    k_transpose_convert<<<dim3(N3E / 32, E_DIM / 32), dim3(32, 8), 0, stream>>>(W_attn, WaT, E_DIM, N3E);
    k_transpose_convert<<<dim3(E_DIM / 32, E_DIM / 32), dim3(32, 8), 0, stream>>>(W_proj, WpT, E_DIM, E_DIM);
    // GEMM1: 128^2 pipelined kernel, grid 768 (3 full CU rounds, 2 resident blocks/CU)
    k_gemm128<1><<<dim3(768), dim3(256), 0, stream>>>(xb, WaT, b_attn, out, qkvb,
                                                      S_DIM, N3E, E_DIM);
    k_transpose_v<<<dim3(E_DIM / 32, S_DIM / 32), dim3(32, 8), 0, stream>>>(qkvb, vT);
    // attention: 48 sub-blocks per head (split-KV for x>=16), 768 blocks, 4 blk/CU capacity
    k_attn<<<dim3(48, H_NUM), dim3(256), 0, stream>>>(qkvb, vT, concat, Ob, ml);
    k_combine<<<dim3(16, H_NUM), dim3(256), 0, stream>>>(Ob, ml, concat);
    // GEMM2: 128^2 pipelined, 1-D grid 256, XCD-swizzled, 2 blocks/CU
    k_gemm128<0><<<dim3(256), dim3(256), 0, stream>>>(concat, WpT, b_proj, out, nullptr,
                                                      S_DIM, E_DIM, E_DIM);
}

// Round 14
// 184.052 us; speedup vs baseline: 1.0997x; 1.0997x over previous
//
#include <hip/hip_runtime.h>
#include <hip/hip_bf16.h>
#include <stdint.h>

#define S_DIM 2048
#define E_DIM 2048
#define H_NUM 16
#define D_HEAD 128
#define N3E 6144

typedef __attribute__((ext_vector_type(8))) short short8;
typedef __attribute__((ext_vector_type(4))) float f32x4;
typedef __attribute__((ext_vector_type(8))) unsigned short ushort8;

#define GLD16(src, dst)                                                          \
    __builtin_amdgcn_global_load_lds((const __attribute__((address_space(1))) void*)(src), \
                                     (__attribute__((address_space(3))) void*)(dst), 16, 0, 0)

__device__ __forceinline__ unsigned short f32_to_bf16_bits(float f) {
    __hip_bfloat16 b = __float2bfloat16(f);
    unsigned short u;
    __builtin_memcpy(&u, &b, 2);
    return u;
}
__device__ __forceinline__ float bf16_bits_to_f32(unsigned short u) {
    unsigned int v = ((unsigned int)u) << 16;
    float f;
    __builtin_memcpy(&f, &v, 4);
    return f;
}

// ---------------- convert f32 -> bf16 (vectorized, 8 elems/thread) ----------
__global__ void k_convert(const float* __restrict__ in, __hip_bfloat16* __restrict__ out, int n) {
    int i = (blockIdx.x * 256 + threadIdx.x) * 8;
    if (i >= n) return;
    float4 a = *(const float4*)(in + i);
    float4 b = *(const float4*)(in + i + 4);
    ushort8 o;
    o[0] = f32_to_bf16_bits(a.x);
    o[1] = f32_to_bf16_bits(a.y);
    o[2] = f32_to_bf16_bits(a.z);
    o[3] = f32_to_bf16_bits(a.w);
    o[4] = f32_to_bf16_bits(b.x);
    o[5] = f32_to_bf16_bits(b.y);
    o[6] = f32_to_bf16_bits(b.z);
    o[7] = f32_to_bf16_bits(b.w);
    *(ushort8*)(out + i) = o;
}

// ------------- transpose + convert: in [R][C] f32 -> out [C][R] bf16 --------
__global__ void k_transpose_convert(const float* __restrict__ in, __hip_bfloat16* __restrict__ out,
                                    int R, int C) {
    __shared__ float tile[32][33];
    int c0 = blockIdx.x * 32, r0 = blockIdx.y * 32;
    int tx = threadIdx.x, ty = threadIdx.y;  // block (32,8)
#pragma unroll
    for (int i = 0; i < 4; ++i) {
        int r = r0 + ty + i * 8;
        tile[ty + i * 8][tx] = in[(size_t)r * C + c0 + tx];
    }
    __syncthreads();
#pragma unroll
    for (int i = 0; i < 4; ++i) {
        int c = c0 + ty + i * 8;
        out[(size_t)c * R + r0 + tx] = __float2bfloat16(tile[tx][ty + i * 8]);
    }
}

// ------------- transpose v slice of qkv (bf16): vT[hd][t] = qkv[t][4096+hd] --
__global__ void k_transpose_v(const __hip_bfloat16* __restrict__ qkv, __hip_bfloat16* __restrict__ vT) {
    __shared__ __hip_bfloat16 tile[32][33];
    int c0 = blockIdx.x * 32, t0 = blockIdx.y * 32;
    int tx = threadIdx.x, ty = threadIdx.y;  // block (32,8)
#pragma unroll
    for (int i = 0; i < 4; ++i) {
        int t = t0 + ty + i * 8;
        tile[ty + i * 8][tx] = qkv[(size_t)t * N3E + 2 * E_DIM + c0 + tx];
    }
    __syncthreads();
#pragma unroll
    for (int i = 0; i < 4; ++i) {
        int c = c0 + ty + i * 8;
        vT[(size_t)c * S_DIM + t0 + tx] = tile[tx][ty + i * 8];
    }
}

// ====== 256x256 GEMM: register-fragment double-buffer + deep LDS ring =======
// (R10 structure, unchanged: ~660 TF plateau for this shape.)
template <int EPI>
__global__ __launch_bounds__(512, 2) void k_gemm256(const __hip_bfloat16* __restrict__ A,
                                                    const __hip_bfloat16* __restrict__ Bt,
                                                    const float* __restrict__ bias,
                                                    float* __restrict__ outF,
                                                    __hip_bfloat16* __restrict__ outB,
                                                    int M, int N, int K) {
    __shared__ __hip_bfloat16 As[4][256 * 32];
    __shared__ __hip_bfloat16 Bs[4][256 * 32];

    const int tid = threadIdx.x;
    const int w = tid >> 6, lane = tid & 63;
    const int lg = lane >> 4, l16 = lane & 15;
    const int wr = w >> 2, wc = w & 3;  // wave grid 2 (M) x 4 (N)
    const int m0 = blockIdx.y * 256, n0 = blockIdx.x * 256;
    const int NT = K >> 5;  // K-tiles of 32

    int srow[2], sk16[2];
#pragma unroll
    for (int j = 0; j < 2; ++j) {
        int slot = j * 512 + tid;
        srow[j] = slot >> 2;
        sk16[j] = (tid & 3) ^ ((slot >> 3) & 3);  // inverse-swizzled source
    }

    auto stageA = [&](int buf, int t) {
#pragma unroll
        for (int j = 0; j < 2; ++j) {
            const __hip_bfloat16* g = A + (size_t)(m0 + srow[j]) * K + t * 32 + sk16[j] * 8;
            GLD16(g, &As[buf][(j * 512 + tid) * 8]);
        }
    };
    auto stageB = [&](int buf, int t) {
#pragma unroll
        for (int j = 0; j < 2; ++j) {
            const __hip_bfloat16* g = Bt + (size_t)(n0 + srow[j]) * K + t * 32 + sk16[j] * 8;
            GLD16(g, &Bs[buf][(j * 512 + tid) * 8]);
        }
    };

    f32x4 acc[8][4];
#pragma unroll
    for (int i = 0; i < 8; ++i)
#pragma unroll
        for (int j = 0; j < 4; ++j) acc[i][j] = {0.f, 0.f, 0.f, 0.f};

    auto read_frags = [&](int buf, short8* f) {
#pragma unroll
        for (int mi = 0; mi < 4; ++mi) {
            int rowL = wr * 128 + mi * 16 + l16;
            f[mi] = *(const short8*)&As[buf][rowL * 32 + ((lg ^ ((rowL >> 1) & 3)) * 8)];
            int rowU = wr * 128 + 64 + mi * 16 + l16;
            f[4 + mi] = *(const short8*)&As[buf][rowU * 32 + ((lg ^ ((rowU >> 1) & 3)) * 8)];
            int brow = wc * 64 + mi * 16 + l16;
            f[8 + mi] = *(const short8*)&Bs[buf][brow * 32 + ((lg ^ ((brow >> 1) & 3)) * 8)];
        }
    };

    stageA(0, 0); stageB(0, 0);
    stageA(1, 1); stageB(1, 1);
    stageA(2, 2); stageB(2, 2);
    asm volatile("s_waitcnt vmcnt(4)" ::: "memory");
    __builtin_amdgcn_s_barrier();

    short8 fX[12], fY[12];
    read_frags(0, fX);

    auto tile_body = [&](int t, short8* curf, short8* nxtf) {
        if (t + 1 < NT) read_frags((t + 1) & 3, nxtf);
        if (t + 3 < NT) {
            stageA((t + 3) & 3, t + 3);
            stageB((t + 3) & 3, t + 3);
        }
        __builtin_amdgcn_sched_barrier(0);
        __builtin_amdgcn_s_setprio(1);
#pragma unroll
        for (int mi = 0; mi < 4; ++mi)
#pragma unroll
            for (int ni = 0; ni < 4; ++ni) {
                acc[mi][ni] = __builtin_amdgcn_mfma_f32_16x16x32_bf16(curf[mi], curf[8 + ni], acc[mi][ni], 0, 0, 0);
                acc[4 + mi][ni] = __builtin_amdgcn_mfma_f32_16x16x32_bf16(curf[4 + mi], curf[8 + ni], acc[4 + mi][ni], 0, 0, 0);
            }
        __builtin_amdgcn_s_setprio(0);
        asm volatile("s_waitcnt lgkmcnt(0)" ::: "memory");
        __builtin_amdgcn_sched_barrier(0);
        if (t == NT - 3)
            asm volatile("s_waitcnt vmcnt(0)" ::: "memory");
        else if (t < NT - 3)
            asm volatile("s_waitcnt vmcnt(4)" ::: "memory");
        __builtin_amdgcn_sched_barrier(0);
        __builtin_amdgcn_s_barrier();
    };

    for (int t = 0; t < NT; t += 2) {
        tile_body(t, fX, fY);
        tile_body(t + 1, fY, fX);
    }

    const size_t OFF_K = (size_t)S_DIM * E_DIM;
    const size_t OFF_V = 2 * (size_t)S_DIM * E_DIM;
#pragma unroll
    for (int ni = 0; ni < 4; ++ni) {
        int jcol = n0 + wc * 64 + ni * 16 + l16;
        float bj = bias[jcol];
#pragma unroll
        for (int mi = 0; mi < 8; ++mi) {
#pragma unroll
            for (int r = 0; r < 4; ++r) {
                int s = m0 + wr * 128 + mi * 16 + lg * 4 + r;
                float v = acc[mi][ni][r] + bj;
                if (EPI == 1) {
                    outB[(size_t)s * N + jcol] = __float2bfloat16(v);
                    if (jcol >= 2 * E_DIM) {
                        outF[OFF_V + (size_t)s * E_DIM + (jcol - 2 * E_DIM)] = v;
                    } else if (jcol >= E_DIM) {
                        outF[OFF_K + (size_t)s * E_DIM + (jcol - E_DIM)] = v;
                    }
                } else {
                    outF[(size_t)s * N + jcol] = v;
                }
            }
        }
    }
}

// ======================= 128x128 pipelined GEMM (GEMM2) ======================
template <int EPI>
__global__ __launch_bounds__(256, 2) void k_gemm128(const __hip_bfloat16* __restrict__ A,
                                                    const __hip_bfloat16* __restrict__ Bt,
                                                    const float* __restrict__ bias,
                                                    float* __restrict__ outF,
                                                    __hip_bfloat16* __restrict__ outB,
                                                    int M, int N, int K) {
    __shared__ __hip_bfloat16 As[4][128 * 32];
    __shared__ __hip_bfloat16 Bs[4][128 * 32];

    const int tid = threadIdx.x;
    const int w = tid >> 6, lane = tid & 63;
    const int lg = lane >> 4, l16 = lane & 15;
    const int wr = w >> 1, wc = w & 1;  // wave grid 2 (M) x 2 (N)
    const int ntx = N >> 7;
    const int chunk = ((M >> 7) * ntx) >> 3;
    const int lin = blockIdx.x;
    const int swz = (lin & 7) * chunk + (lin >> 3);
    const int m0 = (swz / ntx) << 7, n0 = (swz % ntx) << 7;
    const int NT = K >> 5;

    const int srow = tid >> 2;
    const int scol = ((tid & 3) ^ ((tid >> 3) & 3)) * 8;
    const __hip_bfloat16* aB = A + (size_t)(m0 + srow) * K + scol;
    const __hip_bfloat16* bB = Bt + (size_t)(n0 + srow) * K + scol;
    const size_t rstep = (size_t)64 * K;

#define STG(u, p)                                                                                     \
    do {                                                                                              \
        GLD16(aB + (p) * rstep + (u) * 32, &As[(u) & 3][(p) * 2048 + tid * 8]);                       \
        GLD16(bB + (p) * rstep + (u) * 32, &Bs[(u) & 3][(p) * 2048 + tid * 8]);                       \
    } while (0)

    f32x4 acc[4][4];
#pragma unroll
    for (int i = 0; i < 4; ++i)
#pragma unroll
        for (int j = 0; j < 4; ++j) acc[i][j] = {0.f, 0.f, 0.f, 0.f};

    STG(0, 0); STG(0, 1);
    STG(1, 0); STG(1, 1);
    STG(2, 0); STG(2, 1);
    asm volatile("s_waitcnt vmcnt(8)" ::: "memory");
    __builtin_amdgcn_s_barrier();

    short8 af[4], bfr[4];
    for (int t = 0; t < NT; ++t) {
        const int cur = t & 3;
        const int u = t + 3;
#pragma unroll
        for (int i = 0; i < 4; ++i) {
            int arow = wr * 64 + i * 16 + l16;
            af[i] = *(const short8*)&As[cur][arow * 32 + ((lg ^ ((arow >> 1) & 3)) * 8)];
            int brow = wc * 64 + i * 16 + l16;
            bfr[i] = *(const short8*)&Bs[cur][brow * 32 + ((lg ^ ((brow >> 1) & 3)) * 8)];
        }
        if (u < NT) { STG(u, 0); STG(u, 1); }
        __builtin_amdgcn_s_setprio(1);
#pragma unroll
        for (int mi = 0; mi < 4; ++mi)
#pragma unroll
            for (int ni = 0; ni < 4; ++ni)
                acc[mi][ni] = __builtin_amdgcn_mfma_f32_16x16x32_bf16(af[mi], bfr[ni], acc[mi][ni], 0, 0, 0);
        __builtin_amdgcn_s_setprio(0);
        __builtin_amdgcn_sched_barrier(0);
        if (t < NT - 3)
            asm volatile("s_waitcnt vmcnt(8)" ::: "memory");
        else if (t == NT - 3)
            asm volatile("s_waitcnt vmcnt(4)" ::: "memory");
        else if (t == NT - 2)
            asm volatile("s_waitcnt vmcnt(0)" ::: "memory");
        __builtin_amdgcn_sched_barrier(0);
        __builtin_amdgcn_s_barrier();
    }
#undef STG

    const size_t OFF_K = (size_t)S_DIM * E_DIM;
    const size_t OFF_V = 2 * (size_t)S_DIM * E_DIM;
#pragma unroll
    for (int ni = 0; ni < 4; ++ni) {
        int jcol = n0 + wc * 64 + ni * 16 + l16;
        float bj = bias[jcol];
#pragma unroll
        for (int mi = 0; mi < 4; ++mi) {
#pragma unroll
            for (int r = 0; r < 4; ++r) {
                int s = m0 + wr * 64 + mi * 16 + lg * 4 + r;
                float v = acc[mi][ni][r] + bj;
                if (EPI == 1) {
                    outB[(size_t)s * N + jcol] = __float2bfloat16(v);
                    if (jcol >= 2 * E_DIM) {
                        outF[OFF_V + (size_t)s * E_DIM + (jcol - 2 * E_DIM)] = v;
                    } else if (jcol >= E_DIM) {
                        outF[OFF_K + (size_t)s * E_DIM + (jcol - E_DIM)] = v;
                    }
                } else {
                    outF[(size_t)s * N + jcol] = v;
                }
            }
        }
    }
}

// ---------------- flash attention (causal), split-KV, fixed-max softmax -----
// R10's proven sync structure, KVBLK=32: LDS 36.5KB -> 4 blocks/CU.
__global__ __launch_bounds__(256) void k_attn(const __hip_bfloat16* __restrict__ qkv,   // [S][6144]
                                              const __hip_bfloat16* __restrict__ vT,    // [2048][2048]
                                              __hip_bfloat16* __restrict__ concat,      // [S][2048]
                                              __hip_bfloat16* __restrict__ Ob,          // [512][64][128]
                                              float* __restrict__ ml) {                 // [512][64][2]
    const int h = blockIdx.y;
    const int xs = 47 - (int)blockIdx.x;  // longest-work-first-ish dispatch
    int x, tstart, tend, chunk = 0;       // tstart/tend in units of 32-kv tiles
    bool split;
    if (xs < 16) {
        x = xs; tstart = 0; tend = 2 * (x + 1); split = false;
    } else {
        int idx = xs - 16;
        x = 16 + (idx >> 1);
        chunk = idx & 1;
        int L = 2 * (x + 1), half = L >> 1;
        tstart = chunk ? half : 0;
        tend = chunk ? L : half;
        split = true;
    }
    const int q0 = x * 64;
    const int tid = threadIdx.x;
    const int w = tid >> 6, lane = tid & 63;
    const int lg = lane >> 4, l16 = lane & 15;
    const int sbase = q0 + w * 16;
    const float scale = 0.08838834764831845f;  // 1/sqrt(128)
    const float FIXM = 8.0f;

    __shared__ __hip_bfloat16 Ks[2][32 * 128];  // [t][d], swizzled (16-slot rows, ^kr&7)
    __shared__ __hip_bfloat16 Vs[2][128 * 32];  // [d][t], swizzled (4-slot rows, ^d&3)
    __shared__ __hip_bfloat16 plds[4][16 * 36];

    short8 qa[4];
#pragma unroll
    for (int kc = 0; kc < 4; ++kc)
        qa[kc] = *(const short8*)&qkv[(size_t)(sbase + l16) * N3E + h * D_HEAD + kc * 32 + lg * 8];

    short8 ones;
#pragma unroll
    for (int j = 0; j < 8; ++j) ones[j] = (short)0x3F80;  // bf16 1.0

    f32x4 O[8];
#pragma unroll
    for (int i = 0; i < 8; ++i) O[i] = {0.f, 0.f, 0.f, 0.f};
    f32x4 accL = {0.f, 0.f, 0.f, 0.f};  // row-sum of P (replicated over lanes)

    auto stage = [&](int buf, int it) {
        const int t0 = it * 32;
#pragma unroll
        for (int j = 0; j < 2; ++j) {
            int kr = j * 16 + w * 4 + (lane >> 4);
            int ks16 = (lane & 15) ^ (kr & 7);
            const __hip_bfloat16* gk = qkv + (size_t)(t0 + kr) * N3E + E_DIM + h * D_HEAD + ks16 * 8;
            GLD16(gk, &Ks[buf][j * 2048 + w * 512]);
            int vd = j * 64 + w * 16 + (lane >> 2);
            int vs4 = (lane & 3) ^ (vd & 3);
            const __hip_bfloat16* gv = vT + (size_t)(h * D_HEAD + vd) * S_DIM + t0 + vs4 * 8;
            GLD16(gv, &Vs[buf][j * 2048 + w * 512]);
        }
    };

    stage(0, tstart);
    int cur = 0;

    for (int it = tstart; it < tend; ++it) {
        const int t0 = it * 32;
        __syncthreads();  // vmcnt drained: buf[cur] ready; all waves done with buf[cur^1]
        if (it + 1 < tend) stage(cur ^ 1, it + 1);
        const bool diag = (t0 >= q0);

        // ---- QK^T from LDS (swizzled reads): 2 col-tiles x 4 kc = 8 MFMA ----
        f32x4 sc[2];
        __builtin_amdgcn_s_setprio(1);
#pragma unroll
        for (int f = 0; f < 2; ++f) {
            sc[f] = {0.f, 0.f, 0.f, 0.f};
            int r = f * 16 + l16;
#pragma unroll
            for (int kc = 0; kc < 4; ++kc) {
                int ce = (kc * 32 + lg * 8) ^ ((r & 7) << 3);
                short8 kb = *(const short8*)&Ks[cur][r * 128 + ce];
                sc[f] = __builtin_amdgcn_mfma_f32_16x16x32_bf16(qa[kc], kb, sc[f], 0, 0, 0);
            }
        }
        __builtin_amdgcn_s_setprio(0);

        // ---- fixed-max softmax: p = exp(s*scale - 8); no reductions ----
#pragma unroll
        for (int f = 0; f < 2; ++f) {
#pragma unroll
            for (int r = 0; r < 4; ++r) {
                float v = sc[f][r] * scale - FIXM;
                if (diag) {
                    int t = t0 + f * 16 + l16;
                    int s = sbase + lg * 4 + r;
                    if (t > s) v = -1e30f;
                }
                sc[f][r] = __expf(v);
            }
        }

        // ---- P (C-layout) -> LDS -> A-layout fragment ----
#pragma unroll
        for (int f = 0; f < 2; ++f)
#pragma unroll
            for (int r = 0; r < 4; ++r)
                plds[w][(lg * 4 + r) * 36 + f * 16 + l16] = __float2bfloat16(sc[f][r]);
        short8 pa = *(const short8*)&plds[w][l16 * 36 + lg * 8];

        // ---- PV (8) + row-sum (1) from LDS (swizzled reads) ----
        __builtin_amdgcn_s_setprio(1);
        accL = __builtin_amdgcn_mfma_f32_16x16x32_bf16(pa, ones, accL, 0, 0, 0);
#pragma unroll
        for (int f2 = 0; f2 < 8; ++f2) {
            int d = f2 * 16 + l16;
            int ce = (lg ^ (d & 3)) * 8;
            short8 vb = *(const short8*)&Vs[cur][d * 32 + ce];
            O[f2] = __builtin_amdgcn_mfma_f32_16x16x32_bf16(pa, vb, O[f2], 0, 0, 0);
        }
        __builtin_amdgcn_s_setprio(0);
        cur ^= 1;
    }

    if (!split) {
#pragma unroll
        for (int f2 = 0; f2 < 8; ++f2) {
#pragma unroll
            for (int r = 0; r < 4; ++r) {
                int s = sbase + lg * 4 + r;
                float v = O[f2][r] / accL[r];
                concat[(size_t)s * E_DIM + h * D_HEAD + f2 * 16 + l16] = __float2bfloat16(v);
            }
        }
    } else {
        const int sub = (h * 16 + (x - 16)) * 2 + chunk;
#pragma unroll
        for (int f2 = 0; f2 < 8; ++f2) {
#pragma unroll
            for (int r = 0; r < 4; ++r) {
                int row = w * 16 + lg * 4 + r;
                Ob[(size_t)sub * 8192 + row * 128 + f2 * 16 + l16] = __float2bfloat16(O[f2][r]);
            }
        }
        if (l16 == 0) {
#pragma unroll
            for (int r = 0; r < 4; ++r) {
                int row = w * 16 + lg * 4 + r;
                ml[((size_t)sub * 64 + row) * 2 + 0] = FIXM;
                ml[((size_t)sub * 64 + row) * 2 + 1] = accL[r];
            }
        }
    }
}

// ---------------- combine two KV-split partials -> concat -------------------
__global__ __launch_bounds__(256) void k_combine(const __hip_bfloat16* __restrict__ Ob,
                                                 const float* __restrict__ ml,
                                                 __hip_bfloat16* __restrict__ concat) {
    const int xx = blockIdx.x;  // 0..15 -> x = xx+16
    const int h = blockIdx.y;
    const int tid = threadIdx.x;
    const int row = tid >> 2;
    const int d0 = (tid & 3) * 32;
    const int sub0 = (h * 16 + xx) * 2, sub1 = sub0 + 1;
    const float m0 = ml[((size_t)sub0 * 64 + row) * 2 + 0];
    const float l0 = ml[((size_t)sub0 * 64 + row) * 2 + 1];
    const float m1 = ml[((size_t)sub1 * 64 + row) * 2 + 0];
    const float l1 = ml[((size_t)sub1 * 64 + row) * 2 + 1];
    const float M = fmaxf(m0, m1);
    const float w0 = __expf(m0 - M), w1 = __expf(m1 - M);
    const float inv = 1.f / (w0 * l0 + w1 * l1);
    const int s = (xx + 16) * 64 + row;
#pragma unroll
    for (int j = 0; j < 32; j += 8) {
        ushort8 a = *(const ushort8*)&Ob[(size_t)sub0 * 8192 + row * 128 + d0 + j];
        ushort8 b = *(const ushort8*)&Ob[(size_t)sub1 * 8192 + row * 128 + d0 + j];
        ushort8 o;
#pragma unroll
        for (int q = 0; q < 8; ++q) {
            float fa = bf16_bits_to_f32(a[q]);
            float fb = bf16_bits_to_f32(b[q]);
            o[q] = f32_to_bf16_bits((w0 * fa + w1 * fb) * inv);
        }
        *(ushort8*)&concat[(size_t)s * E_DIM + h * D_HEAD + d0 + j] = o;
    }
}

extern "C" void kernel_launch(void* const* d_in, const int* in_sizes, int n_in,
                              void* d_out, int out_size, void* d_ws, size_t ws_size,
                              hipStream_t stream) {
    const float* x = (const float*)d_in[0];
    const float* W_attn = (const float*)d_in[1];
    const float* b_attn = (const float*)d_in[2];
    const float* W_proj = (const float*)d_in[3];
    const float* b_proj = (const float*)d_in[4];
    float* out = (float*)d_out;

    __hip_bfloat16* xb = (__hip_bfloat16*)d_ws;                    // 2048x2048
    __hip_bfloat16* WaT = xb + (size_t)S_DIM * E_DIM;              // 6144x2048
    __hip_bfloat16* WpT = WaT + (size_t)N3E * E_DIM;               // 2048x2048
    __hip_bfloat16* qkvb = WpT + (size_t)E_DIM * E_DIM;            // 2048x6144
    __hip_bfloat16* vT = qkvb + (size_t)S_DIM * N3E;               // 2048x2048
    __hip_bfloat16* concat = xb;                                   // alias (xb dead after GEMM1)
    __hip_bfloat16* Ob = WaT;                                      // 512 x 64 x 128 bf16
    float* ml = (float*)(WaT + (size_t)512 * 8192);                // 512 x 64 x 2 f32

    k_convert<<<dim3((S_DIM * E_DIM) / (256 * 8)), dim3(256), 0, stream>>>(x, xb, S_DIM * E_DIM);
    k_transpose_convert<<<dim3(N3E / 32, E_DIM / 32), dim3(32, 8), 0, stream>>>(W_attn, WaT, E_DIM, N3E);
    k_transpose_convert<<<dim3(E_DIM / 32, E_DIM / 32), dim3(32, 8), 0, stream>>>(W_proj, WpT, E_DIM, E_DIM);
    // GEMM1: 256^2 reg-dbuf kernel, plain 2-D grid 24x8
    k_gemm256<1><<<dim3(N3E / 256, S_DIM / 256), dim3(512), 0, stream>>>(xb, WaT, b_attn, out, qkvb,
                                                                         S_DIM, N3E, E_DIM);
    k_transpose_v<<<dim3(E_DIM / 32, S_DIM / 32), dim3(32, 8), 0, stream>>>(qkvb, vT);
    // attention: 48 sub-blocks per head (split-KV for x>=16), 768 blocks, 4 blk/CU capacity
    k_attn<<<dim3(48, H_NUM), dim3(256), 0, stream>>>(qkvb, vT, concat, Ob, ml);
    k_combine<<<dim3(16, H_NUM), dim3(256), 0, stream>>>(Ob, ml, concat);
    // GEMM2: 128^2 pipelined, 1-D grid 256, XCD-swizzled, 2 blocks/CU
    k_gemm128<0><<<dim3(256), dim3(256), 0, stream>>>(concat, WpT, b_proj, out, nullptr,
                                                      S_DIM, E_DIM, E_DIM);
}